// Round 9
// baseline (280.212 us; speedup 1.0000x reference)
//
#include <hip/hip_runtime.h>
#include <hip/hip_fp16.h>
#include <math.h>

typedef _Float16 f16x8 __attribute__((ext_vector_type(8)));
typedef _Float16 f16x4 __attribute__((ext_vector_type(4)));
typedef float f32x4 __attribute__((ext_vector_type(4)));

__device__ __forceinline__ int f2oi(float f) {
    int i = __float_as_int(f);
    return i >= 0 ? i : (i ^ 0x7FFFFFFF);
}
__device__ __forceinline__ float oi2f(int i) {
    return __int_as_float(i >= 0 ? i : (i ^ 0x7FFFFFFF));
}

// ---------- MFMA GEMM + fused logits + fused global-max ----------
template<int MT, int H>
__global__ __launch_bounds__(256) void gemm_mfma(const float* __restrict__ X,
                                                 const float* __restrict__ W,
                                                 const float* __restrict__ a_src,
                                                 const float* __restrict__ a_dst,
                                                 __half* __restrict__ Hout, int Mout,
                                                 float* __restrict__ als,
                                                 float* __restrict__ ald,
                                                 int* __restrict__ mint, int N) {
    constexpr int LDSB = (MT * 4096 > 16384) ? MT * 4096 : 16384;
    constexpr int HST = (MT == 8) ? 256 : 128;
    __shared__ char ldsb[LDSB];
    __shared__ int lmax[8];

    int tid = threadIdx.x;
    if (tid < 8) lmax[tid] = (int)0x80000000;

    const int nf4 = 16 * MT * 32;
    for (int idx = tid; idx < nf4; idx += 256) {
        int r = idx >> 5, c = idx & 31;
        float4 w = (r < Mout) ? reinterpret_cast<const float4*>(W)[(size_t)r * 32 + c]
                              : make_float4(0.f, 0.f, 0.f, 0.f);
        f16x4 hv;
        hv[0] = (_Float16)w.x; hv[1] = (_Float16)w.y;
        hv[2] = (_Float16)w.z; hv[3] = (_Float16)w.w;
        int byte = r * 256 + ((c * 8) ^ ((r & 7) << 4));
        *reinterpret_cast<f16x4*>(&ldsb[byte]) = hv;
    }
    __syncthreads();

    int l = tid & 63, wv = tid >> 6;
    int lr = l & 15, lk = l >> 4;
    f32x4 acc[2][MT];
#pragma unroll
    for (int rt = 0; rt < 2; rt++)
#pragma unroll
        for (int c = 0; c < MT; c++) acc[rt][c] = (f32x4){0.f, 0.f, 0.f, 0.f};

    const float* xp[2];
#pragma unroll
    for (int rt = 0; rt < 2; rt++) {
        int rg = blockIdx.x * 128 + rt * 64 + wv * 16 + lr;
        if (rg >= N) rg = N - 1;
        xp[rt] = X + (size_t)rg * 128 + lk * 8;
    }

#pragma unroll
    for (int k0 = 0; k0 < 128; k0 += 32) {
        f16x8 a[2];
#pragma unroll
        for (int rt = 0; rt < 2; rt++) {
            float4 x0 = *reinterpret_cast<const float4*>(xp[rt] + k0);
            float4 x1 = *reinterpret_cast<const float4*>(xp[rt] + k0 + 4);
            a[rt][0] = (_Float16)x0.x; a[rt][1] = (_Float16)x0.y;
            a[rt][2] = (_Float16)x0.z; a[rt][3] = (_Float16)x0.w;
            a[rt][4] = (_Float16)x1.x; a[rt][5] = (_Float16)x1.y;
            a[rt][6] = (_Float16)x1.z; a[rt][7] = (_Float16)x1.w;
        }
#pragma unroll
        for (int c = 0; c < MT; c++) {
            int n = 16 * c + lr;
            int byte = n * 256 + (((k0 + lk * 8) * 2) ^ ((n & 7) << 4));
            f16x8 b = *reinterpret_cast<const f16x8*>(&ldsb[byte]);
            acc[0][c] = __builtin_amdgcn_mfma_f32_16x16x32_f16(a[0], b, acc[0][c], 0, 0, 0);
            acc[1][c] = __builtin_amdgcn_mfma_f32_16x16x32_f16(a[1], b, acc[1][c], 0, 0, 0);
        }
    }
    __syncthreads();

#pragma unroll
    for (int rt = 0; rt < 2; rt++)
#pragma unroll
        for (int c = 0; c < MT; c++)
#pragma unroll
            for (int r = 0; r < 4; r++) {
                int rowl = rt * 64 + wv * 16 + lk * 4 + r;
                int col = 16 * c + lr;
                int byte = rowl * HST + ((col * 2) ^ ((rowl & 7) << 4));
                *reinterpret_cast<__half*>(&ldsb[byte]) = __float2half(acc[rt][c][r]);
            }
    __syncthreads();

    int row = tid >> 1, seg = tid & 1;
    int rowg = blockIdx.x * 128 + row;
    if (rowg < N) {
        const int rowB = Mout * 2;
        int segstart = (MT == 8) ? seg * 128 : seg * 48;
        int nch = (MT == 8) ? 8 : (seg ? 2 : 3);
        float hs[H], hd[H];
#pragma unroll
        for (int h = 0; h < H; h++) { hs[h] = 0.f; hd[h] = 0.f; }
        for (int i = 0; i < nch; i++) {
            int cb = segstart + i * 16;
            f16x8 v = *reinterpret_cast<const f16x8*>(
                &ldsb[row * HST + (cb ^ ((row & 7) << 4))]);
            *reinterpret_cast<f16x8*>((char*)Hout + (size_t)rowg * rowB + cb) = v;
            int hh = (H == 1) ? 0 : (cb >> 6);
            int colb = cb >> 1;
            float ps = 0.f, pd = 0.f;
#pragma unroll
            for (int j = 0; j < 8; j++) {
                float f = (float)v[j];
                ps = fmaf(f, a_src[colb + j], ps);
                pd = fmaf(f, a_dst[colb + j], pd);
            }
            hs[hh] += ps; hd[hh] += pd;
        }
        if (H == 4) {
#pragma unroll
            for (int t = 0; t < 2; t++) {
                int hh = 2 * seg + t;
                als[rowg * 4 + hh] = hs[hh];
                ald[rowg * 4 + hh] = hd[hh];
                atomicMax(&lmax[hh], f2oi(hs[hh]));
                atomicMax(&lmax[4 + hh], f2oi(hd[hh]));
            }
        } else {
            float s = hs[0] + __shfl_xor(hs[0], 1, 64);
            float d = hd[0] + __shfl_xor(hd[0], 1, 64);
            if (seg == 0) {
                als[rowg] = s; ald[rowg] = d;
                atomicMax(&lmax[0], f2oi(s));
                atomicMax(&lmax[4], f2oi(d));
            }
        }
    }
    __syncthreads();
    if (tid < H) atomicMax(&mint[tid], lmax[tid]);
    if (tid >= 8 && tid < 8 + H) atomicMax(&mint[4 + tid - 8], lmax[4 + tid - 8]);
}

// ---------- atomic-free CSR build ----------
__global__ __launch_bounds__(256) void p1_hist(const int* __restrict__ src,
                                               const int* __restrict__ dst,
                                               int E_real, int E_tot, int NB, int NBLK,
                                               int EPB, int* __restrict__ cntmat) {
    __shared__ int hist[1024];
    for (int i = threadIdx.x; i < NB; i += 256) hist[i] = 0;
    __syncthreads();
    int e0 = blockIdx.x * EPB;
    int e1 = min(e0 + EPB, E_tot);
    for (int e = e0 + threadIdx.x; e < e1; e += 256) {
        int d = (e < E_real) ? dst[e] : e - E_real;
        atomicAdd(&hist[d >> 6], 1);
    }
    __syncthreads();
    for (int b = threadIdx.x; b < NB; b += 256)
        cntmat[b * NBLK + blockIdx.x] = hist[b];
}

__global__ __launch_bounds__(256) void p_scancols(int* __restrict__ cntmat,
                                                  int* __restrict__ colTot, int NBLK) {
    __shared__ int sh[256];
    int b = blockIdx.x;
    int t = threadIdx.x;
    if (t < NBLK) sh[t] = cntmat[b * NBLK + t];
    __syncthreads();
    if (t == 0) {
        int run = 0;
        for (int i = 0; i < NBLK; i++) { int v = sh[i]; sh[i] = run; run += v; }
        colTot[b] = run;
    }
    __syncthreads();
    if (t < NBLK) cntmat[b * NBLK + t] = sh[t];
}

__global__ __launch_bounds__(256) void p_scancoarse(const int* __restrict__ colTot,
                                                    int* __restrict__ coarseOff,
                                                    int* __restrict__ offsets,
                                                    int NB, int N, int E_tot) {
    __shared__ int sh[256];
    int t = threadIdx.x, base = t * 4;
    int v0 = 0, v1 = 0, v2 = 0, v3 = 0;
    if (base + 0 < NB) v0 = colTot[base + 0];
    if (base + 1 < NB) v1 = colTot[base + 1];
    if (base + 2 < NB) v2 = colTot[base + 2];
    if (base + 3 < NB) v3 = colTot[base + 3];
    int s = v0 + v1 + v2 + v3;
    sh[t] = s;
    __syncthreads();
    for (int off = 1; off < 256; off <<= 1) {
        int u = (t >= off) ? sh[t - off] : 0;
        __syncthreads();
        sh[t] += u;
        __syncthreads();
    }
    int run = sh[t] - s;
    if (base + 0 < NB) { coarseOff[base + 0] = run; run += v0; }
    if (base + 1 < NB) { coarseOff[base + 1] = run; run += v1; }
    if (base + 2 < NB) { coarseOff[base + 2] = run; run += v2; }
    if (base + 3 < NB) { coarseOff[base + 3] = run; }
    if (t == 255) { coarseOff[NB] = sh[255]; offsets[N] = E_tot; }
}

__global__ __launch_bounds__(256) void p2_scatter(const int* __restrict__ src,
                                                  const int* __restrict__ dst,
                                                  int E_real, int E_tot, int NB, int NBLK,
                                                  int EPB, const int* __restrict__ cntmat,
                                                  const int* __restrict__ coarseOff,
                                                  int2* __restrict__ pairs) {
    __shared__ int cur[1024];
    for (int b = threadIdx.x; b < NB; b += 256)
        cur[b] = coarseOff[b] + cntmat[b * NBLK + blockIdx.x];
    __syncthreads();
    int e0 = blockIdx.x * EPB;
    int e1 = min(e0 + EPB, E_tot);
    for (int e = e0 + threadIdx.x; e < e1; e += 256) {
        int s, d;
        if (e < E_real) { s = src[e]; d = dst[e]; } else { s = d = e - E_real; }
        int pos = atomicAdd(&cur[d >> 6], 1);
        pairs[pos] = make_int2(s, d);
    }
}

__global__ __launch_bounds__(256) void p3_bucket(const int2* __restrict__ pairs,
                                                 const int* __restrict__ coarseOff,
                                                 int NB, int N, int* __restrict__ offsets,
                                                 int* __restrict__ csr_src) {
    __shared__ int lh[64], lc[64];
    int b = blockIdx.x;
    int beg = coarseOff[b], end = coarseOff[b + 1];
    int t = threadIdx.x;
    if (t < 64) lh[t] = 0;
    __syncthreads();
    for (int i = beg + t; i < end; i += 256)
        atomicAdd(&lh[pairs[i].y & 63], 1);
    __syncthreads();
    if (t < 64) {
        int v = lh[t];
        int run = v;
#pragma unroll
        for (int off = 1; off < 64; off <<= 1) {
            int o = __shfl_up(run, off, 64);
            if (t >= off) run += o;
        }
        int ex = run - v;
        lc[t] = ex;
        int node = b * 64 + t;
        if (node < N) offsets[node] = beg + ex;
    }
    __syncthreads();
    for (int i = beg + t; i < end; i += 256) {
        int2 p = pairs[i];
        int pos = atomicAdd(&lc[p.y & 63], 1);
        csr_src[beg + pos] = p.x;
    }
}

// ---------- per-edge weight precompute (node-parallel, CSR order) ----------
__global__ __launch_bounds__(256) void edge_w4(const int* __restrict__ offsets,
                                               const int* __restrict__ csr_src,
                                               const float* __restrict__ als,
                                               const float* __restrict__ ald,
                                               const int* __restrict__ mint,
                                               float4* __restrict__ wexp, int N) {
    int lane = threadIdx.x & 63;
    int gwid = (blockIdx.x * 256 + threadIdx.x) >> 6;
    int nWaves = (gridDim.x * 256) >> 6;
    const float4* als4 = (const float4*)als;
    const float4* ald4 = (const float4*)ald;
    float4 shift;
    {
        float v;
        v = oi2f(mint[0]) + oi2f(mint[4]); shift.x = v > 0.f ? v : 0.2f * v;
        v = oi2f(mint[1]) + oi2f(mint[5]); shift.y = v > 0.f ? v : 0.2f * v;
        v = oi2f(mint[2]) + oi2f(mint[6]); shift.z = v > 0.f ? v : 0.2f * v;
        v = oi2f(mint[3]) + oi2f(mint[7]); shift.w = v > 0.f ? v : 0.2f * v;
    }
    for (int n = gwid; n < N; n += nWaves) {
        int beg = offsets[n], end = offsets[n + 1];
        float4 adn = ald4[n];
        for (int e = beg + lane; e < end; e += 64) {
            int s = csr_src[e];
            float4 a4 = als4[s];
            float4 w; float v;
            v = a4.x + adn.x; v = v > 0.f ? v : 0.2f * v; w.x = __expf(v - shift.x);
            v = a4.y + adn.y; v = v > 0.f ? v : 0.2f * v; w.y = __expf(v - shift.y);
            v = a4.z + adn.z; v = v > 0.f ? v : 0.2f * v; w.z = __expf(v - shift.z);
            v = a4.w + adn.w; v = v > 0.f ? v : 0.2f * v; w.w = __expf(v - shift.w);
            wexp[e] = w;
        }
    }
}

__global__ __launch_bounds__(256) void edge_w1(const int* __restrict__ offsets,
                                               const int* __restrict__ csr_src,
                                               const float* __restrict__ als,
                                               const float* __restrict__ ald,
                                               const int* __restrict__ mint,
                                               float* __restrict__ wexp, int N) {
    int lane = threadIdx.x & 63;
    int gwid = (blockIdx.x * 256 + threadIdx.x) >> 6;
    int nWaves = (gridDim.x * 256) >> 6;
    float shift;
    {
        float v = oi2f(mint[0]) + oi2f(mint[4]);
        shift = v > 0.f ? v : 0.2f * v;
    }
    for (int n = gwid; n < N; n += nWaves) {
        int beg = offsets[n], end = offsets[n + 1];
        float adn = ald[n];
        for (int e = beg + lane; e < end; e += 64) {
            int s = csr_src[e];
            float v = als[s] + adn; v = v > 0.f ? v : 0.2f * v;
            wexp[e] = __expf(v - shift);
        }
    }
}

// ---------- GAT aggregate, layers 0/1 (H=4,C=32): pure stream+gather ----------
__global__ __launch_bounds__(256) void gat_agg128(const int* __restrict__ offsets,
                                                  const int* __restrict__ csr_src,
                                                  const __half* __restrict__ h,
                                                  const float* __restrict__ wexp,
                                                  const float* __restrict__ bias,
                                                  float* __restrict__ out, int N) {
    int lane = threadIdx.x & 63;
    int gwid = (blockIdx.x * 256 + threadIdx.x) >> 6;
    int nWaves = (gridDim.x * 256) >> 6;
    int hh = lane >> 4;
    const __half2* h2 = (const __half2*)h;
    float2 bv = ((const float2*)bias)[lane];

    for (int n = gwid; n < N; n += nWaves) {
        int beg = offsets[n], end = offsets[n + 1];
        float accx = 0.f, accy = 0.f, den = 0.f;
        int p = beg;
        for (; p + 8 <= end; p += 8) {
            float w[8]; int s[8];
#pragma unroll
            for (int j = 0; j < 8; j++) {
                w[j] = wexp[(size_t)(p + j) * 4 + hh];
                s[j] = csr_src[p + j];
            }
#pragma unroll
            for (int j = 0; j < 8; j++) {
                float2 f = __half22float2(h2[(size_t)s[j] * 64 + lane]);
                den += w[j];
                accx = fmaf(f.x, w[j], accx);
                accy = fmaf(f.y, w[j], accy);
            }
        }
        for (; p < end; ++p) {
            float w0 = wexp[(size_t)p * 4 + hh];
            int s0 = csr_src[p];
            float2 f = __half22float2(h2[(size_t)s0 * 64 + lane]);
            den += w0;
            accx = fmaf(f.x, w0, accx);
            accy = fmaf(f.y, w0, accy);
        }
        float inv = 1.f / den;
        float r0 = accx * inv + bv.x;
        float r1 = accy * inv + bv.y;
        float2 o;
        o.x = r0 > 0.f ? r0 : expm1f(r0);
        o.y = r1 > 0.f ? r1 : expm1f(r1);
        ((float2*)out)[(size_t)n * 64 + lane] = o;
    }
}

// ---------- GAT aggregate + log_softmax, layer 2 (H=1,C=40) ----------
__global__ __launch_bounds__(256) void gat_agg40_lsm(const int* __restrict__ offsets,
                                                     const int* __restrict__ csr_src,
                                                     const __half* __restrict__ h,
                                                     const float* __restrict__ wexp,
                                                     const float* __restrict__ b2,
                                                     float* __restrict__ out, int N) {
    int lane = threadIdx.x & 63;
    int gwid = (blockIdx.x * 256 + threadIdx.x) >> 6;
    int nWaves = (gridDim.x * 256) >> 6;

    for (int n = gwid; n < N; n += nWaves) {
        int beg = offsets[n], end = offsets[n + 1];
        float acc = 0.f, den = 0.f;
        int p = beg;
        for (; p + 8 <= end; p += 8) {
            float w[8]; int s[8];
#pragma unroll
            for (int j = 0; j < 8; j++) {
                w[j] = wexp[p + j];
                s[j] = csr_src[p + j];
            }
#pragma unroll
            for (int j = 0; j < 8; j++) {
                float hv = (lane < 40) ? __half2float(h[(size_t)s[j] * 40 + lane]) : 0.f;
                den += w[j];
                acc = fmaf(hv, w[j], acc);
            }
        }
        for (; p < end; ++p) {
            float w0 = wexp[p];
            int s0 = csr_src[p];
            float hv = (lane < 40) ? __half2float(h[(size_t)s0 * 40 + lane]) : 0.f;
            den += w0;
            acc = fmaf(hv, w0, acc);
        }
        float val = (lane < 40) ? acc / den + b2[lane] : -INFINITY;
        float mx = val;
#pragma unroll
        for (int off = 32; off >= 1; off >>= 1) mx = fmaxf(mx, __shfl_xor(mx, off, 64));
        float pe = (lane < 40) ? __expf(val - mx) : 0.f;
        float sum = pe;
#pragma unroll
        for (int off = 32; off >= 1; off >>= 1) sum += __shfl_xor(sum, off, 64);
        if (lane < 40) out[n * 40 + lane] = val - mx - logf(sum);
    }
}

extern "C" void kernel_launch(void* const* d_in, const int* in_sizes, int n_in,
                              void* d_out, int out_size, void* d_ws, size_t ws_size,
                              hipStream_t stream) {
    const float* x      = (const float*)d_in[0];
    const int*   ei     = (const int*)d_in[1];
    const float* W0     = (const float*)d_in[2];
    const float* a_src0 = (const float*)d_in[3];
    const float* a_dst0 = (const float*)d_in[4];
    const float* b0     = (const float*)d_in[5];
    const float* W1     = (const float*)d_in[6];
    const float* a_src1 = (const float*)d_in[7];
    const float* a_dst1 = (const float*)d_in[8];
    const float* b1     = (const float*)d_in[9];
    const float* W2     = (const float*)d_in[10];
    const float* a_src2 = (const float*)d_in[11];
    const float* a_dst2 = (const float*)d_in[12];
    const float* b2     = (const float*)d_in[13];

    const int N = in_sizes[0] / 128;          // 50000
    const int E_real = in_sizes[1] / 2;       // 800000
    const int E_tot = E_real + N;
    const int* src = ei;
    const int* dst = ei + E_real;

    const int EPB  = 4096;
    const int NBLK = (E_tot + EPB - 1) / EPB; // 208
    const int NB   = (N + 63) >> 6;           // 782

    unsigned char* ws = (unsigned char*)d_ws;
    size_t off = 0;
    __half* bufH    = (__half*)(ws + off); off += (size_t)N * 128 * sizeof(__half);
    float*  bufAcc  = (float*)(ws + off);  off += (size_t)N * 128 * sizeof(float);
    int*    csr_src = (int*)(ws + off);    off += (size_t)E_tot * sizeof(int);
    float*  als     = (float*)(ws + off);  off += (size_t)N * 4 * sizeof(float);
    float*  ald     = (float*)(ws + off);  off += (size_t)N * 4 * sizeof(float);
    int*    offsets = (int*)(ws + off);    off += (size_t)(N + 1) * sizeof(int);
    int*    colTot  = (int*)(ws + off);    off += (size_t)NB * sizeof(int);
    int*    coarseOff = (int*)(ws + off);  off += (size_t)(NB + 1) * sizeof(int);
    int*    mint    = (int*)(ws + off);    off += 24 * sizeof(int);
    int*    cntmat  = (int*)(ws + off);    off += (size_t)NB * NBLK * sizeof(int);
    off = (off + 15) & ~(size_t)15;
    // union region: pairs (E*8B, CSR build only) / wexp (E*16B, per layer)
    int2*   pairs   = (int2*)(ws + off);
    float*  wexp    = (float*)(ws + off);  off += (size_t)E_tot * 4 * sizeof(float);

    const int B = 256;
    const int gRows128 = (N + 127) / 128;
    const int gAgg  = 2048;

    // ===== CSR build (atomic-free) =====
    hipMemsetAsync(mint, 0x80, 24 * sizeof(int), stream);
    p1_hist<<<NBLK, B, 0, stream>>>(src, dst, E_real, E_tot, NB, NBLK, EPB, cntmat);
    p_scancols<<<NB, B, 0, stream>>>(cntmat, colTot, NBLK);
    p_scancoarse<<<1, B, 0, stream>>>(colTot, coarseOff, offsets, NB, N, E_tot);
    p2_scatter<<<NBLK, B, 0, stream>>>(src, dst, E_real, E_tot, NB, NBLK, EPB, cntmat, coarseOff, pairs);
    p3_bucket<<<NB, B, 0, stream>>>(pairs, coarseOff, NB, N, offsets, csr_src);

    // ===== Layer 0 =====
    gemm_mfma<8, 4><<<gRows128, B, 0, stream>>>(x, W0, a_src0, a_dst0, bufH, 128, als, ald, mint, N);
    edge_w4<<<gAgg, B, 0, stream>>>(offsets, csr_src, als, ald, mint, (float4*)wexp, N);
    gat_agg128<<<gAgg, B, 0, stream>>>(offsets, csr_src, bufH, wexp, b0, bufAcc, N);

    // ===== Layer 1 =====
    gemm_mfma<8, 4><<<gRows128, B, 0, stream>>>(bufAcc, W1, a_src1, a_dst1, bufH, 128, als, ald, mint + 8, N);
    edge_w4<<<gAgg, B, 0, stream>>>(offsets, csr_src, als, ald, mint + 8, (float4*)wexp, N);
    gat_agg128<<<gAgg, B, 0, stream>>>(offsets, csr_src, bufH, wexp, b1, bufAcc, N);

    // ===== Layer 2 =====
    gemm_mfma<3, 1><<<gRows128, B, 0, stream>>>(bufAcc, W2, a_src2, a_dst2, bufH, 40, als, ald, mint + 16, N);
    edge_w1<<<gAgg, B, 0, stream>>>(offsets, csr_src, als, ald, mint + 16, wexp, N);
    gat_agg40_lsm<<<gAgg, B, 0, stream>>>(offsets, csr_src, bufH, wexp, b2,
                                          (float*)d_out, N);
}

// Round 10
// 222.362 us; speedup vs baseline: 1.2602x; 1.2602x over previous
//
#include <hip/hip_runtime.h>
#include <hip/hip_fp16.h>
#include <math.h>

typedef _Float16 f16x8 __attribute__((ext_vector_type(8)));
typedef _Float16 f16x4 __attribute__((ext_vector_type(4)));
typedef float f32x4 __attribute__((ext_vector_type(4)));

__device__ __forceinline__ int f2oi(float f) {
    int i = __float_as_int(f);
    return i >= 0 ? i : (i ^ 0x7FFFFFFF);
}
__device__ __forceinline__ float oi2f(int i) {
    return __int_as_float(i >= 0 ? i : (i ^ 0x7FFFFFFF));
}

// ---------- MFMA GEMM + fused logits + fused global-max ----------
template<int MT, int H>
__global__ __launch_bounds__(256) void gemm_mfma(const float* __restrict__ X,
                                                 const float* __restrict__ W,
                                                 const float* __restrict__ a_src,
                                                 const float* __restrict__ a_dst,
                                                 __half* __restrict__ Hout, int Mout,
                                                 float* __restrict__ als,
                                                 float* __restrict__ ald,
                                                 int* __restrict__ mint, int N) {
    constexpr int LDSB = (MT * 4096 > 16384) ? MT * 4096 : 16384;
    constexpr int HST = (MT == 8) ? 256 : 128;
    __shared__ char ldsb[LDSB];
    __shared__ int lmax[8];

    int tid = threadIdx.x;
    if (tid < 8) lmax[tid] = (int)0x80000000;

    const int nf4 = 16 * MT * 32;
    for (int idx = tid; idx < nf4; idx += 256) {
        int r = idx >> 5, c = idx & 31;
        float4 w = (r < Mout) ? reinterpret_cast<const float4*>(W)[(size_t)r * 32 + c]
                              : make_float4(0.f, 0.f, 0.f, 0.f);
        f16x4 hv;
        hv[0] = (_Float16)w.x; hv[1] = (_Float16)w.y;
        hv[2] = (_Float16)w.z; hv[3] = (_Float16)w.w;
        int byte = r * 256 + ((c * 8) ^ ((r & 7) << 4));
        *reinterpret_cast<f16x4*>(&ldsb[byte]) = hv;
    }
    __syncthreads();

    int l = tid & 63, wv = tid >> 6;
    int lr = l & 15, lk = l >> 4;
    f32x4 acc[2][MT];
#pragma unroll
    for (int rt = 0; rt < 2; rt++)
#pragma unroll
        for (int c = 0; c < MT; c++) acc[rt][c] = (f32x4){0.f, 0.f, 0.f, 0.f};

    const float* xp[2];
#pragma unroll
    for (int rt = 0; rt < 2; rt++) {
        int rg = blockIdx.x * 128 + rt * 64 + wv * 16 + lr;
        if (rg >= N) rg = N - 1;
        xp[rt] = X + (size_t)rg * 128 + lk * 8;
    }

#pragma unroll
    for (int k0 = 0; k0 < 128; k0 += 32) {
        f16x8 a[2];
#pragma unroll
        for (int rt = 0; rt < 2; rt++) {
            float4 x0 = *reinterpret_cast<const float4*>(xp[rt] + k0);
            float4 x1 = *reinterpret_cast<const float4*>(xp[rt] + k0 + 4);
            a[rt][0] = (_Float16)x0.x; a[rt][1] = (_Float16)x0.y;
            a[rt][2] = (_Float16)x0.z; a[rt][3] = (_Float16)x0.w;
            a[rt][4] = (_Float16)x1.x; a[rt][5] = (_Float16)x1.y;
            a[rt][6] = (_Float16)x1.z; a[rt][7] = (_Float16)x1.w;
        }
#pragma unroll
        for (int c = 0; c < MT; c++) {
            int n = 16 * c + lr;
            int byte = n * 256 + (((k0 + lk * 8) * 2) ^ ((n & 7) << 4));
            f16x8 b = *reinterpret_cast<const f16x8*>(&ldsb[byte]);
            acc[0][c] = __builtin_amdgcn_mfma_f32_16x16x32_f16(a[0], b, acc[0][c], 0, 0, 0);
            acc[1][c] = __builtin_amdgcn_mfma_f32_16x16x32_f16(a[1], b, acc[1][c], 0, 0, 0);
        }
    }
    __syncthreads();

#pragma unroll
    for (int rt = 0; rt < 2; rt++)
#pragma unroll
        for (int c = 0; c < MT; c++)
#pragma unroll
            for (int r = 0; r < 4; r++) {
                int rowl = rt * 64 + wv * 16 + lk * 4 + r;
                int col = 16 * c + lr;
                int byte = rowl * HST + ((col * 2) ^ ((rowl & 7) << 4));
                *reinterpret_cast<__half*>(&ldsb[byte]) = __float2half(acc[rt][c][r]);
            }
    __syncthreads();

    int row = tid >> 1, seg = tid & 1;
    int rowg = blockIdx.x * 128 + row;
    if (rowg < N) {
        const int rowB = Mout * 2;
        int segstart = (MT == 8) ? seg * 128 : seg * 48;
        int nch = (MT == 8) ? 8 : (seg ? 2 : 3);
        float hs[H], hd[H];
#pragma unroll
        for (int h = 0; h < H; h++) { hs[h] = 0.f; hd[h] = 0.f; }
        for (int i = 0; i < nch; i++) {
            int cb = segstart + i * 16;
            f16x8 v = *reinterpret_cast<const f16x8*>(
                &ldsb[row * HST + (cb ^ ((row & 7) << 4))]);
            *reinterpret_cast<f16x8*>((char*)Hout + (size_t)rowg * rowB + cb) = v;
            int hh = (H == 1) ? 0 : (cb >> 6);
            int colb = cb >> 1;
            float ps = 0.f, pd = 0.f;
#pragma unroll
            for (int j = 0; j < 8; j++) {
                float f = (float)v[j];
                ps = fmaf(f, a_src[colb + j], ps);
                pd = fmaf(f, a_dst[colb + j], pd);
            }
            hs[hh] += ps; hd[hh] += pd;
        }
        if (H == 4) {
#pragma unroll
            for (int t = 0; t < 2; t++) {
                int hh = 2 * seg + t;
                als[rowg * 4 + hh] = hs[hh];
                ald[rowg * 4 + hh] = hd[hh];
                atomicMax(&lmax[hh], f2oi(hs[hh]));
                atomicMax(&lmax[4 + hh], f2oi(hd[hh]));
            }
        } else {
            float s = hs[0] + __shfl_xor(hs[0], 1, 64);
            float d = hd[0] + __shfl_xor(hd[0], 1, 64);
            if (seg == 0) {
                als[rowg] = s; ald[rowg] = d;
                atomicMax(&lmax[0], f2oi(s));
                atomicMax(&lmax[4], f2oi(d));
            }
        }
    }
    __syncthreads();
    if (tid < H) atomicMax(&mint[tid], lmax[tid]);
    if (tid >= 8 && tid < 8 + H) atomicMax(&mint[4 + tid - 8], lmax[4 + tid - 8]);
}

// ---------- atomic-free CSR build (packed src<<16|dst pairs; N < 65536) ----------
__global__ __launch_bounds__(256) void p1_hist(const int* __restrict__ src,
                                               const int* __restrict__ dst,
                                               int E_real, int E_tot, int NB, int NBLK,
                                               int EPB, int* __restrict__ cntmat) {
    __shared__ int hist[1024];
    for (int i = threadIdx.x; i < NB; i += 256) hist[i] = 0;
    __syncthreads();
    int e0 = blockIdx.x * EPB;
    int e1 = min(e0 + EPB, E_tot);
    for (int e = e0 + threadIdx.x; e < e1; e += 256) {
        int d = (e < E_real) ? dst[e] : e - E_real;
        atomicAdd(&hist[d >> 6], 1);
    }
    __syncthreads();
    for (int b = threadIdx.x; b < NB; b += 256)
        cntmat[b * NBLK + blockIdx.x] = hist[b];
}

__global__ __launch_bounds__(256) void p_scancols(int* __restrict__ cntmat,
                                                  int* __restrict__ colTot, int NBLK) {
    __shared__ int sh[256];
    int b = blockIdx.x;
    int t = threadIdx.x;
    if (t < NBLK) sh[t] = cntmat[b * NBLK + t];
    __syncthreads();
    if (t == 0) {
        int run = 0;
        for (int i = 0; i < NBLK; i++) { int v = sh[i]; sh[i] = run; run += v; }
        colTot[b] = run;
    }
    __syncthreads();
    if (t < NBLK) cntmat[b * NBLK + t] = sh[t];
}

__global__ __launch_bounds__(256) void p_scancoarse(const int* __restrict__ colTot,
                                                    int* __restrict__ coarseOff,
                                                    int* __restrict__ offsets,
                                                    int NB, int N, int E_tot) {
    __shared__ int sh[256];
    int t = threadIdx.x, base = t * 4;
    int v0 = 0, v1 = 0, v2 = 0, v3 = 0;
    if (base + 0 < NB) v0 = colTot[base + 0];
    if (base + 1 < NB) v1 = colTot[base + 1];
    if (base + 2 < NB) v2 = colTot[base + 2];
    if (base + 3 < NB) v3 = colTot[base + 3];
    int s = v0 + v1 + v2 + v3;
    sh[t] = s;
    __syncthreads();
    for (int off = 1; off < 256; off <<= 1) {
        int u = (t >= off) ? sh[t - off] : 0;
        __syncthreads();
        sh[t] += u;
        __syncthreads();
    }
    int run = sh[t] - s;
    if (base + 0 < NB) { coarseOff[base + 0] = run; run += v0; }
    if (base + 1 < NB) { coarseOff[base + 1] = run; run += v1; }
    if (base + 2 < NB) { coarseOff[base + 2] = run; run += v2; }
    if (base + 3 < NB) { coarseOff[base + 3] = run; }
    if (t == 255) { coarseOff[NB] = sh[255]; offsets[N] = E_tot; }
}

__global__ __launch_bounds__(256) void p2_scatter(const int* __restrict__ src,
                                                  const int* __restrict__ dst,
                                                  int E_real, int E_tot, int NB, int NBLK,
                                                  int EPB, const int* __restrict__ cntmat,
                                                  const int* __restrict__ coarseOff,
                                                  int* __restrict__ pairs) {
    __shared__ int cur[1024];
    for (int b = threadIdx.x; b < NB; b += 256)
        cur[b] = coarseOff[b] + cntmat[b * NBLK + blockIdx.x];
    __syncthreads();
    int e0 = blockIdx.x * EPB;
    int e1 = min(e0 + EPB, E_tot);
    for (int e = e0 + threadIdx.x; e < e1; e += 256) {
        int s, d;
        if (e < E_real) { s = src[e]; d = dst[e]; } else { s = d = e - E_real; }
        int pos = atomicAdd(&cur[d >> 6], 1);
        pairs[pos] = (s << 16) | d;
    }
}

__global__ __launch_bounds__(256) void p3_bucket(const int* __restrict__ pairs,
                                                 const int* __restrict__ coarseOff,
                                                 int NB, int N, int* __restrict__ offsets,
                                                 int* __restrict__ csr_src) {
    __shared__ int lh[64], lc[64];
    int b = blockIdx.x;
    int beg = coarseOff[b], end = coarseOff[b + 1];
    int t = threadIdx.x;
    if (t < 64) lh[t] = 0;
    __syncthreads();
    for (int i = beg + t; i < end; i += 256)
        atomicAdd(&lh[pairs[i] & 63], 1);
    __syncthreads();
    if (t < 64) {
        int v = lh[t];
        int run = v;
#pragma unroll
        for (int off = 1; off < 64; off <<= 1) {
            int o = __shfl_up(run, off, 64);
            if (t >= off) run += o;
        }
        int ex = run - v;
        lc[t] = ex;
        int node = b * 64 + t;
        if (node < N) offsets[node] = beg + ex;
    }
    __syncthreads();
    for (int i = beg + t; i < end; i += 256) {
        int pk = pairs[i];
        int pos = atomicAdd(&lc[pk & 63], 1);
        csr_src[beg + pos] = ((unsigned)pk) >> 16;
    }
}

// ---------- GAT aggregate, layers 0/1 (H=4,C=32): 4 edges in flight ----------
// Wave = 4 groups x 16 lanes. Group g takes edge p+g; lane j gathers 8 fp16 ch (16B).
__global__ __launch_bounds__(256) void gat_agg128(const int* __restrict__ offsets,
                                                  const int* __restrict__ csr_src,
                                                  const __half* __restrict__ h,
                                                  const float* __restrict__ als,
                                                  const float* __restrict__ ald,
                                                  const int* __restrict__ mint,
                                                  const float* __restrict__ bias,
                                                  float* __restrict__ out, int N) {
    __shared__ float wlds[4][64][4];
    __shared__ int   slds[4][64];
    int wid = threadIdx.x >> 6;
    int lane = threadIdx.x & 63;
    int g = lane >> 4, j = lane & 15, hd = j >> 2;
    int gwid = (blockIdx.x * 256 + threadIdx.x) >> 6;
    int nWaves = (gridDim.x * 256) >> 6;
    const f16x8* h8 = (const f16x8*)h;
    const float4* als4 = (const float4*)als;
    const float4* ald4 = (const float4*)ald;

    float4 shiftv;
    {
        float v;
        v = oi2f(mint[0]) + oi2f(mint[4]); shiftv.x = v > 0.f ? v : 0.2f * v;
        v = oi2f(mint[1]) + oi2f(mint[5]); shiftv.y = v > 0.f ? v : 0.2f * v;
        v = oi2f(mint[2]) + oi2f(mint[6]); shiftv.z = v > 0.f ? v : 0.2f * v;
        v = oi2f(mint[3]) + oi2f(mint[7]); shiftv.w = v > 0.f ? v : 0.2f * v;
    }
    float4 bv0 = ((const float4*)bias)[j * 2];
    float4 bv1 = ((const float4*)bias)[j * 2 + 1];

    for (int n = gwid; n < N; n += nWaves) {
        int beg = offsets[n], end = offsets[n + 1];
        float4 adn = ald4[n];
        float acc[8];
#pragma unroll
        for (int k = 0; k < 8; k++) acc[k] = 0.f;
        float den = 0.f;

        for (int c0 = beg; c0 < end; c0 += 64) {
            int e = c0 + lane;
            if (e < end) {
                int s = csr_src[e];
                float4 a4 = als4[s];
                float4 w; float v;
                v = a4.x + adn.x; v = v > 0.f ? v : 0.2f * v; w.x = __expf(v - shiftv.x);
                v = a4.y + adn.y; v = v > 0.f ? v : 0.2f * v; w.y = __expf(v - shiftv.y);
                v = a4.z + adn.z; v = v > 0.f ? v : 0.2f * v; w.z = __expf(v - shiftv.z);
                v = a4.w + adn.w; v = v > 0.f ? v : 0.2f * v; w.w = __expf(v - shiftv.w);
                *reinterpret_cast<float4*>(&wlds[wid][lane][0]) = w;
                slds[wid][lane] = s;
            }
            int cnt = end - c0; if (cnt > 64) cnt = 64;
            for (int p = 0; p < cnt; p += 4) {
                int e2 = p + g;
                int ec = (e2 < cnt) ? e2 : cnt - 1;
                int s = slds[wid][ec];
                float w = wlds[wid][ec][hd];
                if (e2 >= cnt) w = 0.f;
                f16x8 hv = h8[(size_t)s * 16 + j];
                den += w;
#pragma unroll
                for (int k = 0; k < 8; k++)
                    acc[k] = fmaf((float)hv[k], w, acc[k]);
            }
        }
        // combine the 4 groups
#pragma unroll
        for (int off = 16; off <= 32; off <<= 1) {
            den += __shfl_xor(den, off, 64);
#pragma unroll
            for (int k = 0; k < 8; k++) acc[k] += __shfl_xor(acc[k], off, 64);
        }
        if (g == 0) {
            float inv = 1.f / den;
            float4 o0, o1;
            float r;
            r = acc[0] * inv + bv0.x; o0.x = r > 0.f ? r : expm1f(r);
            r = acc[1] * inv + bv0.y; o0.y = r > 0.f ? r : expm1f(r);
            r = acc[2] * inv + bv0.z; o0.z = r > 0.f ? r : expm1f(r);
            r = acc[3] * inv + bv0.w; o0.w = r > 0.f ? r : expm1f(r);
            r = acc[4] * inv + bv1.x; o1.x = r > 0.f ? r : expm1f(r);
            r = acc[5] * inv + bv1.y; o1.y = r > 0.f ? r : expm1f(r);
            r = acc[6] * inv + bv1.z; o1.z = r > 0.f ? r : expm1f(r);
            r = acc[7] * inv + bv1.w; o1.w = r > 0.f ? r : expm1f(r);
            float4* op = (float4*)(out + (size_t)n * 128 + j * 8);
            op[0] = o0; op[1] = o1;
        }
    }
}

// ---------- GAT aggregate + log_softmax, layer 2 (H=1,C=40) ----------
__global__ __launch_bounds__(256) void gat_agg40_lsm(const int* __restrict__ offsets,
                                                     const int* __restrict__ csr_src,
                                                     const __half* __restrict__ h,
                                                     const float* __restrict__ als,
                                                     const float* __restrict__ ald,
                                                     const int* __restrict__ mint,
                                                     const float* __restrict__ b2,
                                                     float* __restrict__ out, int N) {
    __shared__ float wlds[4][64];
    __shared__ int   slds[4][64];
    int wid = threadIdx.x >> 6;
    int lane = threadIdx.x & 63;
    int g = lane >> 4, j = lane & 15;
    int gwid = (blockIdx.x * 256 + threadIdx.x) >> 6;
    int nWaves = (gridDim.x * 256) >> 6;

    float shift;
    {
        float v = oi2f(mint[0]) + oi2f(mint[4]);
        shift = v > 0.f ? v : 0.2f * v;
    }
    float4 bv = (j < 10) ? ((const float4*)b2)[j] : make_float4(0.f, 0.f, 0.f, 0.f);

    for (int n = gwid; n < N; n += nWaves) {
        int beg = offsets[n], end = offsets[n + 1];
        float adn = ald[n];
        float acc[4];
#pragma unroll
        for (int k = 0; k < 4; k++) acc[k] = 0.f;
        float den = 0.f;

        for (int c0 = beg; c0 < end; c0 += 64) {
            int e = c0 + lane;
            if (e < end) {
                int s = csr_src[e];
                float v = als[s] + adn; v = v > 0.f ? v : 0.2f * v;
                wlds[wid][lane] = __expf(v - shift);
                slds[wid][lane] = s;
            }
            int cnt = end - c0; if (cnt > 64) cnt = 64;
            for (int p = 0; p < cnt; p += 4) {
                int e2 = p + g;
                int ec = (e2 < cnt) ? e2 : cnt - 1;
                int s = slds[wid][ec];
                float w = wlds[wid][ec];
                if (e2 >= cnt) w = 0.f;
                den += w;
                if (j < 10) {
                    f16x4 hv = reinterpret_cast<const f16x4*>(h + (size_t)s * 40)[j];
#pragma unroll
                    for (int k = 0; k < 4; k++)
                        acc[k] = fmaf((float)hv[k], w, acc[k]);
                }
            }
        }
#pragma unroll
        for (int off = 16; off <= 32; off <<= 1) {
            den += __shfl_xor(den, off, 64);
#pragma unroll
            for (int k = 0; k < 4; k++) acc[k] += __shfl_xor(acc[k], off, 64);
        }
        float inv = 1.f / den;
        float val[4];
        float m = -INFINITY;
#pragma unroll
        for (int k = 0; k < 4; k++) {
            val[k] = (j < 10) ? acc[k] * inv + ((const float*)&bv)[k] : -INFINITY;
            m = fmaxf(m, val[k]);
        }
#pragma unroll
        for (int off = 8; off >= 1; off >>= 1) m = fmaxf(m, __shfl_xor(m, off, 64));
        float pe = 0.f;
#pragma unroll
        for (int k = 0; k < 4; k++)
            if (j < 10) pe += __expf(val[k] - m);
#pragma unroll
        for (int off = 8; off >= 1; off >>= 1) pe += __shfl_xor(pe, off, 64);
        if (g == 0 && j < 10) {
            float lsum = logf(pe);
            float4 o;
            o.x = val[0] - m - lsum;
            o.y = val[1] - m - lsum;
            o.z = val[2] - m - lsum;
            o.w = val[3] - m - lsum;
            ((float4*)(out + (size_t)n * 40))[j] = o;
        }
    }
}

extern "C" void kernel_launch(void* const* d_in, const int* in_sizes, int n_in,
                              void* d_out, int out_size, void* d_ws, size_t ws_size,
                              hipStream_t stream) {
    const float* x      = (const float*)d_in[0];
    const int*   ei     = (const int*)d_in[1];
    const float* W0     = (const float*)d_in[2];
    const float* a_src0 = (const float*)d_in[3];
    const float* a_dst0 = (const float*)d_in[4];
    const float* b0     = (const float*)d_in[5];
    const float* W1     = (const float*)d_in[6];
    const float* a_src1 = (const float*)d_in[7];
    const float* a_dst1 = (const float*)d_in[8];
    const float* b1     = (const float*)d_in[9];
    const float* W2     = (const float*)d_in[10];
    const float* a_src2 = (const float*)d_in[11];
    const float* a_dst2 = (const float*)d_in[12];
    const float* b2     = (const float*)d_in[13];

    const int N = in_sizes[0] / 128;          // 50000  (< 65536, required for packing)
    const int E_real = in_sizes[1] / 2;       // 800000
    const int E_tot = E_real + N;
    const int* src = ei;
    const int* dst = ei + E_real;

    const int EPB  = 4096;
    const int NBLK = (E_tot + EPB - 1) / EPB; // 208
    const int NB   = (N + 63) >> 6;           // 782

    unsigned char* ws = (unsigned char*)d_ws;
    size_t off = 0;
    __half* bufH    = (__half*)(ws + off); off += (size_t)N * 128 * sizeof(__half);
    float*  bufAcc  = (float*)(ws + off);  off += (size_t)N * 128 * sizeof(float);
    int*    csr_src = (int*)(ws + off);    off += (size_t)E_tot * sizeof(int);
    int*    pairs   = (int*)(ws + off);    off += (size_t)E_tot * sizeof(int);
    float*  als     = (float*)(ws + off);  off += (size_t)N * 4 * sizeof(float);
    float*  ald     = (float*)(ws + off);  off += (size_t)N * 4 * sizeof(float);
    int*    offsets = (int*)(ws + off);    off += (size_t)(N + 1) * sizeof(int);
    int*    colTot  = (int*)(ws + off);    off += (size_t)NB * sizeof(int);
    int*    coarseOff = (int*)(ws + off);  off += (size_t)(NB + 1) * sizeof(int);
    int*    mint    = (int*)(ws + off);    off += 24 * sizeof(int);
    int*    cntmat  = (int*)(ws + off);    off += (size_t)NB * NBLK * sizeof(int);

    const int B = 256;
    const int gRows128 = (N + 127) / 128;
    const int gAgg  = 2048;

    // ===== CSR build (atomic-free) =====
    hipMemsetAsync(mint, 0x80, 24 * sizeof(int), stream);
    p1_hist<<<NBLK, B, 0, stream>>>(src, dst, E_real, E_tot, NB, NBLK, EPB, cntmat);
    p_scancols<<<NB, B, 0, stream>>>(cntmat, colTot, NBLK);
    p_scancoarse<<<1, B, 0, stream>>>(colTot, coarseOff, offsets, NB, N, E_tot);
    p2_scatter<<<NBLK, B, 0, stream>>>(src, dst, E_real, E_tot, NB, NBLK, EPB, cntmat, coarseOff, pairs);
    p3_bucket<<<NB, B, 0, stream>>>(pairs, coarseOff, NB, N, offsets, csr_src);

    // ===== Layer 0 =====
    gemm_mfma<8, 4><<<gRows128, B, 0, stream>>>(x, W0, a_src0, a_dst0, bufH, 128, als, ald, mint, N);
    gat_agg128<<<gAgg, B, 0, stream>>>(offsets, csr_src, bufH, als, ald, mint, b0, bufAcc, N);

    // ===== Layer 1 =====
    gemm_mfma<8, 4><<<gRows128, B, 0, stream>>>(bufAcc, W1, a_src1, a_dst1, bufH, 128, als, ald, mint + 8, N);
    gat_agg128<<<gAgg, B, 0, stream>>>(offsets, csr_src, bufH, als, ald, mint + 8, b1, bufAcc, N);

    // ===== Layer 2 =====
    gemm_mfma<3, 1><<<gRows128, B, 0, stream>>>(bufAcc, W2, a_src2, a_dst2, bufH, 40, als, ald, mint + 16, N);
    gat_agg40_lsm<<<gAgg, B, 0, stream>>>(offsets, csr_src, bufH, als, ald, mint + 16, b2,
                                          (float*)d_out, N);
}

// Round 11
// 204.923 us; speedup vs baseline: 1.3674x; 1.0851x over previous
//
#include <hip/hip_runtime.h>
#include <hip/hip_fp16.h>
#include <math.h>

typedef _Float16 f16x8 __attribute__((ext_vector_type(8)));
typedef _Float16 f16x4 __attribute__((ext_vector_type(4)));
typedef float f32x4 __attribute__((ext_vector_type(4)));

__device__ __forceinline__ int f2oi(float f) {
    int i = __float_as_int(f);
    return i >= 0 ? i : (i ^ 0x7FFFFFFF);
}
__device__ __forceinline__ float oi2f(int i) {
    return __int_as_float(i >= 0 ? i : (i ^ 0x7FFFFFFF));
}

// ---------- MFMA GEMM + fused logits + fused global-max ----------
template<int MT, int H>
__global__ __launch_bounds__(256) void gemm_mfma(const float* __restrict__ X,
                                                 const float* __restrict__ W,
                                                 const float* __restrict__ a_src,
                                                 const float* __restrict__ a_dst,
                                                 __half* __restrict__ Hout, int Mout,
                                                 float* __restrict__ als,
                                                 float* __restrict__ ald,
                                                 int* __restrict__ mint, int N) {
    constexpr int LDSB = (MT * 4096 > 16384) ? MT * 4096 : 16384;
    constexpr int HST = (MT == 8) ? 256 : 128;
    __shared__ char ldsb[LDSB];
    __shared__ int lmax[8];

    int tid = threadIdx.x;
    if (tid < 8) lmax[tid] = (int)0x80000000;

    const int nf4 = 16 * MT * 32;
    for (int idx = tid; idx < nf4; idx += 256) {
        int r = idx >> 5, c = idx & 31;
        float4 w = (r < Mout) ? reinterpret_cast<const float4*>(W)[(size_t)r * 32 + c]
                              : make_float4(0.f, 0.f, 0.f, 0.f);
        f16x4 hv;
        hv[0] = (_Float16)w.x; hv[1] = (_Float16)w.y;
        hv[2] = (_Float16)w.z; hv[3] = (_Float16)w.w;
        int byte = r * 256 + ((c * 8) ^ ((r & 7) << 4));
        *reinterpret_cast<f16x4*>(&ldsb[byte]) = hv;
    }
    __syncthreads();

    int l = tid & 63, wv = tid >> 6;
    int lr = l & 15, lk = l >> 4;
    f32x4 acc[2][MT];
#pragma unroll
    for (int rt = 0; rt < 2; rt++)
#pragma unroll
        for (int c = 0; c < MT; c++) acc[rt][c] = (f32x4){0.f, 0.f, 0.f, 0.f};

    const float* xp[2];
#pragma unroll
    for (int rt = 0; rt < 2; rt++) {
        int rg = blockIdx.x * 128 + rt * 64 + wv * 16 + lr;
        if (rg >= N) rg = N - 1;
        xp[rt] = X + (size_t)rg * 128 + lk * 8;
    }

#pragma unroll
    for (int k0 = 0; k0 < 128; k0 += 32) {
        f16x8 a[2];
#pragma unroll
        for (int rt = 0; rt < 2; rt++) {
            float4 x0 = *reinterpret_cast<const float4*>(xp[rt] + k0);
            float4 x1 = *reinterpret_cast<const float4*>(xp[rt] + k0 + 4);
            a[rt][0] = (_Float16)x0.x; a[rt][1] = (_Float16)x0.y;
            a[rt][2] = (_Float16)x0.z; a[rt][3] = (_Float16)x0.w;
            a[rt][4] = (_Float16)x1.x; a[rt][5] = (_Float16)x1.y;
            a[rt][6] = (_Float16)x1.z; a[rt][7] = (_Float16)x1.w;
        }
#pragma unroll
        for (int c = 0; c < MT; c++) {
            int n = 16 * c + lr;
            int byte = n * 256 + (((k0 + lk * 8) * 2) ^ ((n & 7) << 4));
            f16x8 b = *reinterpret_cast<const f16x8*>(&ldsb[byte]);
            acc[0][c] = __builtin_amdgcn_mfma_f32_16x16x32_f16(a[0], b, acc[0][c], 0, 0, 0);
            acc[1][c] = __builtin_amdgcn_mfma_f32_16x16x32_f16(a[1], b, acc[1][c], 0, 0, 0);
        }
    }
    __syncthreads();

#pragma unroll
    for (int rt = 0; rt < 2; rt++)
#pragma unroll
        for (int c = 0; c < MT; c++)
#pragma unroll
            for (int r = 0; r < 4; r++) {
                int rowl = rt * 64 + wv * 16 + lk * 4 + r;
                int col = 16 * c + lr;
                int byte = rowl * HST + ((col * 2) ^ ((rowl & 7) << 4));
                *reinterpret_cast<__half*>(&ldsb[byte]) = __float2half(acc[rt][c][r]);
            }
    __syncthreads();

    int row = tid >> 1, seg = tid & 1;
    int rowg = blockIdx.x * 128 + row;
    if (rowg < N) {
        const int rowB = Mout * 2;
        int segstart = (MT == 8) ? seg * 128 : seg * 48;
        int nch = (MT == 8) ? 8 : (seg ? 2 : 3);
        float hs[H], hd[H];
#pragma unroll
        for (int h = 0; h < H; h++) { hs[h] = 0.f; hd[h] = 0.f; }
        for (int i = 0; i < nch; i++) {
            int cb = segstart + i * 16;
            f16x8 v = *reinterpret_cast<const f16x8*>(
                &ldsb[row * HST + (cb ^ ((row & 7) << 4))]);
            *reinterpret_cast<f16x8*>((char*)Hout + (size_t)rowg * rowB + cb) = v;
            int hh = (H == 1) ? 0 : (cb >> 6);
            int colb = cb >> 1;
            float ps = 0.f, pd = 0.f;
#pragma unroll
            for (int j = 0; j < 8; j++) {
                float f = (float)v[j];
                ps = fmaf(f, a_src[colb + j], ps);
                pd = fmaf(f, a_dst[colb + j], pd);
            }
            hs[hh] += ps; hd[hh] += pd;
        }
        if (H == 4) {
#pragma unroll
            for (int t = 0; t < 2; t++) {
                int hh = 2 * seg + t;
                als[rowg * 4 + hh] = hs[hh];
                ald[rowg * 4 + hh] = hd[hh];
                atomicMax(&lmax[hh], f2oi(hs[hh]));
                atomicMax(&lmax[4 + hh], f2oi(hd[hh]));
            }
        } else {
            float s = hs[0] + __shfl_xor(hs[0], 1, 64);
            float d = hd[0] + __shfl_xor(hd[0], 1, 64);
            if (seg == 0) {
                als[rowg] = s; ald[rowg] = d;
                atomicMax(&lmax[0], f2oi(s));
                atomicMax(&lmax[4], f2oi(d));
            }
        }
    }
    __syncthreads();
    if (tid < H) atomicMax(&mint[tid], lmax[tid]);
    if (tid >= 8 && tid < 8 + H) atomicMax(&mint[4 + tid - 8], lmax[4 + tid - 8]);
}

// ---------- atomic-free CSR build (packed src<<16|dst pairs; N < 65536) ----------
__global__ __launch_bounds__(256) void p1_hist(const int* __restrict__ src,
                                               const int* __restrict__ dst,
                                               int E_real, int E_tot, int NB, int NBLK,
                                               int EPB, int* __restrict__ cntmat,
                                               int* __restrict__ mint) {
    if (blockIdx.x == 0 && threadIdx.x < 24) mint[threadIdx.x] = (int)0x80000000;
    __shared__ int hist[1024];
    for (int i = threadIdx.x; i < NB; i += 256) hist[i] = 0;
    __syncthreads();
    int e0 = blockIdx.x * EPB;
    int e1 = min(e0 + EPB, E_tot);
    for (int e = e0 + threadIdx.x; e < e1; e += 256) {
        int d = (e < E_real) ? dst[e] : e - E_real;
        atomicAdd(&hist[d >> 6], 1);
    }
    __syncthreads();
    for (int b = threadIdx.x; b < NB; b += 256)
        cntmat[b * NBLK + blockIdx.x] = hist[b];
}

__global__ __launch_bounds__(256) void p_scancols(int* __restrict__ cntmat,
                                                  int* __restrict__ colTot, int NBLK) {
    __shared__ int sh[256];
    int b = blockIdx.x;
    int t = threadIdx.x;
    if (t < NBLK) sh[t] = cntmat[b * NBLK + t];
    __syncthreads();
    if (t == 0) {
        int run = 0;
        for (int i = 0; i < NBLK; i++) { int v = sh[i]; sh[i] = run; run += v; }
        colTot[b] = run;
    }
    __syncthreads();
    if (t < NBLK) cntmat[b * NBLK + t] = sh[t];
}

__global__ __launch_bounds__(256) void p_scancoarse(const int* __restrict__ colTot,
                                                    int* __restrict__ coarseOff,
                                                    int* __restrict__ offsets,
                                                    int NB, int N, int E_tot) {
    __shared__ int sh[256];
    int t = threadIdx.x, base = t * 4;
    int v0 = 0, v1 = 0, v2 = 0, v3 = 0;
    if (base + 0 < NB) v0 = colTot[base + 0];
    if (base + 1 < NB) v1 = colTot[base + 1];
    if (base + 2 < NB) v2 = colTot[base + 2];
    if (base + 3 < NB) v3 = colTot[base + 3];
    int s = v0 + v1 + v2 + v3;
    sh[t] = s;
    __syncthreads();
    for (int off = 1; off < 256; off <<= 1) {
        int u = (t >= off) ? sh[t - off] : 0;
        __syncthreads();
        sh[t] += u;
        __syncthreads();
    }
    int run = sh[t] - s;
    if (base + 0 < NB) { coarseOff[base + 0] = run; run += v0; }
    if (base + 1 < NB) { coarseOff[base + 1] = run; run += v1; }
    if (base + 2 < NB) { coarseOff[base + 2] = run; run += v2; }
    if (base + 3 < NB) { coarseOff[base + 3] = run; }
    if (t == 255) { coarseOff[NB] = sh[255]; offsets[N] = E_tot; }
}

__global__ __launch_bounds__(256) void p2_scatter(const int* __restrict__ src,
                                                  const int* __restrict__ dst,
                                                  int E_real, int E_tot, int NB, int NBLK,
                                                  int EPB, const int* __restrict__ cntmat,
                                                  const int* __restrict__ coarseOff,
                                                  int* __restrict__ pairs) {
    __shared__ int cur[1024];
    for (int b = threadIdx.x; b < NB; b += 256)
        cur[b] = coarseOff[b] + cntmat[b * NBLK + blockIdx.x];
    __syncthreads();
    int e0 = blockIdx.x * EPB;
    int e1 = min(e0 + EPB, E_tot);
    for (int e = e0 + threadIdx.x; e < e1; e += 256) {
        int s, d;
        if (e < E_real) { s = src[e]; d = dst[e]; } else { s = d = e - E_real; }
        int pos = atomicAdd(&cur[d >> 6], 1);
        pairs[pos] = (s << 16) | d;
    }
}

__global__ __launch_bounds__(256) void p3_bucket(const int* __restrict__ pairs,
                                                 const int* __restrict__ coarseOff,
                                                 int NB, int N, int* __restrict__ offsets,
                                                 int* __restrict__ csr_src) {
    __shared__ int lh[64], lc[64];
    int b = blockIdx.x;
    int beg = coarseOff[b], end = coarseOff[b + 1];
    int t = threadIdx.x;
    if (t < 64) lh[t] = 0;
    __syncthreads();
    for (int i = beg + t; i < end; i += 256)
        atomicAdd(&lh[pairs[i] & 63], 1);
    __syncthreads();
    if (t < 64) {
        int v = lh[t];
        int run = v;
#pragma unroll
        for (int off = 1; off < 64; off <<= 1) {
            int o = __shfl_up(run, off, 64);
            if (t >= off) run += o;
        }
        int ex = run - v;
        lc[t] = ex;
        int node = b * 64 + t;
        if (node < N) offsets[node] = beg + ex;
    }
    __syncthreads();
    for (int i = beg + t; i < end; i += 256) {
        int pk = pairs[i];
        int pos = atomicAdd(&lc[pk & 63], 1);
        csr_src[beg + pos] = ((unsigned)pk) >> 16;
    }
}

// ---------- GAT aggregate, layers 0/1 (H=4,C=32): 4 edges in flight ----------
__global__ __launch_bounds__(256) void gat_agg128(const int* __restrict__ offsets,
                                                  const int* __restrict__ csr_src,
                                                  const __half* __restrict__ h,
                                                  const float* __restrict__ als,
                                                  const float* __restrict__ ald,
                                                  const int* __restrict__ mint,
                                                  const float* __restrict__ bias,
                                                  float* __restrict__ out, int N) {
    __shared__ float wlds[4][64][4];
    __shared__ int   slds[4][64];
    int wid = threadIdx.x >> 6;
    int lane = threadIdx.x & 63;
    int g = lane >> 4, j = lane & 15, hd = j >> 2;
    int gwid = (blockIdx.x * 256 + threadIdx.x) >> 6;
    int nWaves = (gridDim.x * 256) >> 6;
    const char* hb = (const char*)h;
    const float4* als4 = (const float4*)als;
    const float4* ald4 = (const float4*)ald;

    float4 shiftv;
    {
        float v;
        v = oi2f(mint[0]) + oi2f(mint[4]); shiftv.x = v > 0.f ? v : 0.2f * v;
        v = oi2f(mint[1]) + oi2f(mint[5]); shiftv.y = v > 0.f ? v : 0.2f * v;
        v = oi2f(mint[2]) + oi2f(mint[6]); shiftv.z = v > 0.f ? v : 0.2f * v;
        v = oi2f(mint[3]) + oi2f(mint[7]); shiftv.w = v > 0.f ? v : 0.2f * v;
    }
    float4 bv0 = ((const float4*)bias)[j * 2];
    float4 bv1 = ((const float4*)bias)[j * 2 + 1];

    for (int n = gwid; n < N; n += nWaves) {
        int beg = offsets[n], end = offsets[n + 1];
        float4 adn = ald4[n];
        float acc[8];
#pragma unroll
        for (int k = 0; k < 8; k++) acc[k] = 0.f;
        float den = 0.f;

        for (int c0 = beg; c0 < end; c0 += 64) {
            int e = c0 + lane;
            // all 64 lanes write (pad with w=0) -> clamp-free inner loop
            int s = 0;
            float4 w = make_float4(0.f, 0.f, 0.f, 0.f);
            if (e < end) {
                s = csr_src[e];
                float4 a4 = als4[s];
                float v;
                v = a4.x + adn.x; v = v > 0.f ? v : 0.2f * v; w.x = __expf(v - shiftv.x);
                v = a4.y + adn.y; v = v > 0.f ? v : 0.2f * v; w.y = __expf(v - shiftv.y);
                v = a4.z + adn.z; v = v > 0.f ? v : 0.2f * v; w.z = __expf(v - shiftv.z);
                v = a4.w + adn.w; v = v > 0.f ? v : 0.2f * v; w.w = __expf(v - shiftv.w);
            }
            *reinterpret_cast<float4*>(&wlds[wid][lane][0]) = w;
            slds[wid][lane] = s;
            int cnt = end - c0; if (cnt > 64) cnt = 64;
            int quads = (cnt + 3) >> 2;
            for (int q = 0; q < quads; ++q) {
                int ec = q * 4 + g;
                int s0 = slds[wid][ec];
                float w0 = wlds[wid][ec][hd];
                f16x8 hv = *reinterpret_cast<const f16x8*>(
                    hb + (unsigned)(s0 * 256 + j * 16));
                den += w0;
#pragma unroll
                for (int k = 0; k < 8; k++)
                    acc[k] = fmaf((float)hv[k], w0, acc[k]);
            }
        }
#pragma unroll
        for (int off = 16; off <= 32; off <<= 1) {
            den += __shfl_xor(den, off, 64);
#pragma unroll
            for (int k = 0; k < 8; k++) acc[k] += __shfl_xor(acc[k], off, 64);
        }
        if (g == 0) {
            float inv = 1.f / den;
            float4 o0, o1;
            float r;
            r = acc[0] * inv + bv0.x; o0.x = r > 0.f ? r : __expf(r) - 1.f;
            r = acc[1] * inv + bv0.y; o0.y = r > 0.f ? r : __expf(r) - 1.f;
            r = acc[2] * inv + bv0.z; o0.z = r > 0.f ? r : __expf(r) - 1.f;
            r = acc[3] * inv + bv0.w; o0.w = r > 0.f ? r : __expf(r) - 1.f;
            r = acc[4] * inv + bv1.x; o1.x = r > 0.f ? r : __expf(r) - 1.f;
            r = acc[5] * inv + bv1.y; o1.y = r > 0.f ? r : __expf(r) - 1.f;
            r = acc[6] * inv + bv1.z; o1.z = r > 0.f ? r : __expf(r) - 1.f;
            r = acc[7] * inv + bv1.w; o1.w = r > 0.f ? r : __expf(r) - 1.f;
            float4* op = (float4*)(out + (size_t)n * 128 + j * 8);
            op[0] = o0; op[1] = o1;
        }
    }
}

// ---------- GAT aggregate + log_softmax, layer 2 (H=1,C=40) ----------
__global__ __launch_bounds__(256) void gat_agg40_lsm(const int* __restrict__ offsets,
                                                     const int* __restrict__ csr_src,
                                                     const __half* __restrict__ h,
                                                     const float* __restrict__ als,
                                                     const float* __restrict__ ald,
                                                     const int* __restrict__ mint,
                                                     const float* __restrict__ b2,
                                                     float* __restrict__ out, int N) {
    __shared__ float wlds[4][64];
    __shared__ int   slds[4][64];
    int wid = threadIdx.x >> 6;
    int lane = threadIdx.x & 63;
    int g = lane >> 4, j = lane & 15;
    int gwid = (blockIdx.x * 256 + threadIdx.x) >> 6;
    int nWaves = (gridDim.x * 256) >> 6;
    const char* hb = (const char*)h;

    float shift;
    {
        float v = oi2f(mint[0]) + oi2f(mint[4]);
        shift = v > 0.f ? v : 0.2f * v;
    }
    float4 bv = (j < 10) ? ((const float4*)b2)[j] : make_float4(0.f, 0.f, 0.f, 0.f);

    for (int n = gwid; n < N; n += nWaves) {
        int beg = offsets[n], end = offsets[n + 1];
        float adn = ald[n];
        float acc[4];
#pragma unroll
        for (int k = 0; k < 4; k++) acc[k] = 0.f;
        float den = 0.f;

        for (int c0 = beg; c0 < end; c0 += 64) {
            int e = c0 + lane;
            int s = 0;
            float wv = 0.f;
            if (e < end) {
                s = csr_src[e];
                float v = als[s] + adn; v = v > 0.f ? v : 0.2f * v;
                wv = __expf(v - shift);
            }
            wlds[wid][lane] = wv;
            slds[wid][lane] = s;
            int cnt = end - c0; if (cnt > 64) cnt = 64;
            int quads = (cnt + 3) >> 2;
            for (int q = 0; q < quads; ++q) {
                int ec = q * 4 + g;
                int s0 = slds[wid][ec];
                float w0 = wlds[wid][ec];
                den += w0;
                if (j < 10) {
                    f16x4 hv = *reinterpret_cast<const f16x4*>(
                        hb + (unsigned)(s0 * 80 + j * 8));
#pragma unroll
                    for (int k = 0; k < 4; k++)
                        acc[k] = fmaf((float)hv[k], w0, acc[k]);
                }
            }
        }
#pragma unroll
        for (int off = 16; off <= 32; off <<= 1) {
            den += __shfl_xor(den, off, 64);
#pragma unroll
            for (int k = 0; k < 4; k++) acc[k] += __shfl_xor(acc[k], off, 64);
        }
        float inv = 1.f / den;
        float val[4];
        float m = -INFINITY;
#pragma unroll
        for (int k = 0; k < 4; k++) {
            val[k] = (j < 10) ? acc[k] * inv + ((const float*)&bv)[k] : -INFINITY;
            m = fmaxf(m, val[k]);
        }
#pragma unroll
        for (int off = 8; off >= 1; off >>= 1) m = fmaxf(m, __shfl_xor(m, off, 64));
        float pe = 0.f;
#pragma unroll
        for (int k = 0; k < 4; k++)
            if (j < 10) pe += __expf(val[k] - m);
#pragma unroll
        for (int off = 8; off >= 1; off >>= 1) pe += __shfl_xor(pe, off, 64);
        if (g == 0 && j < 10) {
            float lsum = __logf(pe);
            float4 o;
            o.x = val[0] - m - lsum;
            o.y = val[1] - m - lsum;
            o.z = val[2] - m - lsum;
            o.w = val[3] - m - lsum;
            ((float4*)(out + (size_t)n * 40))[j] = o;
        }
    }
}

extern "C" void kernel_launch(void* const* d_in, const int* in_sizes, int n_in,
                              void* d_out, int out_size, void* d_ws, size_t ws_size,
                              hipStream_t stream) {
    const float* x      = (const float*)d_in[0];
    const int*   ei     = (const int*)d_in[1];
    const float* W0     = (const float*)d_in[2];
    const float* a_src0 = (const float*)d_in[3];
    const float* a_dst0 = (const float*)d_in[4];
    const float* b0     = (const float*)d_in[5];
    const float* W1     = (const float*)d_in[6];
    const float* a_src1 = (const float*)d_in[7];
    const float* a_dst1 = (const float*)d_in[8];
    const float* b1     = (const float*)d_in[9];
    const float* W2     = (const float*)d_in[10];
    const float* a_src2 = (const float*)d_in[11];
    const float* a_dst2 = (const float*)d_in[12];
    const float* b2     = (const float*)d_in[13];

    const int N = in_sizes[0] / 128;          // 50000  (< 65536, required for packing)
    const int E_real = in_sizes[1] / 2;       // 800000
    const int E_tot = E_real + N;
    const int* src = ei;
    const int* dst = ei + E_real;

    const int EPB  = 4096;
    const int NBLK = (E_tot + EPB - 1) / EPB; // 208
    const int NB   = (N + 63) >> 6;           // 782

    unsigned char* ws = (unsigned char*)d_ws;
    size_t off = 0;
    __half* bufH    = (__half*)(ws + off); off += (size_t)N * 128 * sizeof(__half);
    float*  bufAcc  = (float*)(ws + off);  off += (size_t)N * 128 * sizeof(float);
    int*    csr_src = (int*)(ws + off);    off += (size_t)E_tot * sizeof(int);
    int*    pairs   = (int*)(ws + off);    off += (size_t)E_tot * sizeof(int);
    float*  als     = (float*)(ws + off);  off += (size_t)N * 4 * sizeof(float);
    float*  ald     = (float*)(ws + off);  off += (size_t)N * 4 * sizeof(float);
    int*    offsets = (int*)(ws + off);    off += (size_t)(N + 1) * sizeof(int);
    int*    colTot  = (int*)(ws + off);    off += (size_t)NB * sizeof(int);
    int*    coarseOff = (int*)(ws + off);  off += (size_t)(NB + 1) * sizeof(int);
    int*    mint    = (int*)(ws + off);    off += 24 * sizeof(int);
    int*    cntmat  = (int*)(ws + off);    off += (size_t)NB * NBLK * sizeof(int);

    const int B = 256;
    const int gRows128 = (N + 127) / 128;
    const int gAgg  = 2048;

    // ===== CSR build (atomic-free; mint init fused into p1) =====
    p1_hist<<<NBLK, B, 0, stream>>>(src, dst, E_real, E_tot, NB, NBLK, EPB, cntmat, mint);
    p_scancols<<<NB, B, 0, stream>>>(cntmat, colTot, NBLK);
    p_scancoarse<<<1, B, 0, stream>>>(colTot, coarseOff, offsets, NB, N, E_tot);
    p2_scatter<<<NBLK, B, 0, stream>>>(src, dst, E_real, E_tot, NB, NBLK, EPB, cntmat, coarseOff, pairs);
    p3_bucket<<<NB, B, 0, stream>>>(pairs, coarseOff, NB, N, offsets, csr_src);

    // ===== Layer 0 =====
    gemm_mfma<8, 4><<<gRows128, B, 0, stream>>>(x, W0, a_src0, a_dst0, bufH, 128, als, ald, mint, N);
    gat_agg128<<<gAgg, B, 0, stream>>>(offsets, csr_src, bufH, als, ald, mint, b0, bufAcc, N);

    // ===== Layer 1 =====
    gemm_mfma<8, 4><<<gRows128, B, 0, stream>>>(bufAcc, W1, a_src1, a_dst1, bufH, 128, als, ald, mint + 8, N);
    gat_agg128<<<gAgg, B, 0, stream>>>(offsets, csr_src, bufH, als, ald, mint + 8, b1, bufAcc, N);

    // ===== Layer 2 =====
    gemm_mfma<3, 1><<<gRows128, B, 0, stream>>>(bufAcc, W2, a_src2, a_dst2, bufH, 40, als, ald, mint + 16, N);
    gat_agg40_lsm<<<gAgg, B, 0, stream>>>(offsets, csr_src, bufH, als, ald, mint + 16, b2,
                                          (float*)d_out, N);
}

// Round 12
// 199.945 us; speedup vs baseline: 1.4014x; 1.0249x over previous
//
#include <hip/hip_runtime.h>
#include <hip/hip_fp16.h>
#include <math.h>

typedef _Float16 f16x8 __attribute__((ext_vector_type(8)));
typedef _Float16 f16x4 __attribute__((ext_vector_type(4)));
typedef float f32x4 __attribute__((ext_vector_type(4)));

__device__ __forceinline__ int f2oi(float f) {
    int i = __float_as_int(f);
    return i >= 0 ? i : (i ^ 0x7FFFFFFF);
}
__device__ __forceinline__ float oi2f(int i) {
    return __int_as_float(i >= 0 ? i : (i ^ 0x7FFFFFFF));
}

// ---------- MFMA GEMM + fused logits + fused global-max ----------
// XF16: input rows are fp16 (bufAcc); else fp32.
template<int MT, int H, bool XF16>
__global__ __launch_bounds__(256) void gemm_mfma(const void* __restrict__ Xv,
                                                 const float* __restrict__ W,
                                                 const float* __restrict__ a_src,
                                                 const float* __restrict__ a_dst,
                                                 __half* __restrict__ Hout, int Mout,
                                                 float* __restrict__ als,
                                                 float* __restrict__ ald,
                                                 int* __restrict__ mint, int N) {
    constexpr int LDSB = (MT * 4096 > 16384) ? MT * 4096 : 16384;
    constexpr int HST = (MT == 8) ? 256 : 128;
    __shared__ char ldsb[LDSB];
    __shared__ int lmax[8];

    int tid = threadIdx.x;
    if (tid < 8) lmax[tid] = (int)0x80000000;

    const int nf4 = 16 * MT * 32;
    for (int idx = tid; idx < nf4; idx += 256) {
        int r = idx >> 5, c = idx & 31;
        float4 w = (r < Mout) ? reinterpret_cast<const float4*>(W)[(size_t)r * 32 + c]
                              : make_float4(0.f, 0.f, 0.f, 0.f);
        f16x4 hv;
        hv[0] = (_Float16)w.x; hv[1] = (_Float16)w.y;
        hv[2] = (_Float16)w.z; hv[3] = (_Float16)w.w;
        int byte = r * 256 + ((c * 8) ^ ((r & 7) << 4));
        *reinterpret_cast<f16x4*>(&ldsb[byte]) = hv;
    }
    __syncthreads();

    int l = tid & 63, wv = tid >> 6;
    int lr = l & 15, lk = l >> 4;
    f32x4 acc[2][MT];
#pragma unroll
    for (int rt = 0; rt < 2; rt++)
#pragma unroll
        for (int c = 0; c < MT; c++) acc[rt][c] = (f32x4){0.f, 0.f, 0.f, 0.f};

    const float* xpf[2];
    const __half* xph[2];
#pragma unroll
    for (int rt = 0; rt < 2; rt++) {
        int rg = blockIdx.x * 128 + rt * 64 + wv * 16 + lr;
        if (rg >= N) rg = N - 1;
        if (XF16) xph[rt] = (const __half*)Xv + (size_t)rg * 128 + lk * 8;
        else      xpf[rt] = (const float*)Xv + (size_t)rg * 128 + lk * 8;
    }

#pragma unroll
    for (int k0 = 0; k0 < 128; k0 += 32) {
        f16x8 a[2];
#pragma unroll
        for (int rt = 0; rt < 2; rt++) {
            if (XF16) {
                a[rt] = *reinterpret_cast<const f16x8*>(xph[rt] + k0);
            } else {
                float4 x0 = *reinterpret_cast<const float4*>(xpf[rt] + k0);
                float4 x1 = *reinterpret_cast<const float4*>(xpf[rt] + k0 + 4);
                a[rt][0] = (_Float16)x0.x; a[rt][1] = (_Float16)x0.y;
                a[rt][2] = (_Float16)x0.z; a[rt][3] = (_Float16)x0.w;
                a[rt][4] = (_Float16)x1.x; a[rt][5] = (_Float16)x1.y;
                a[rt][6] = (_Float16)x1.z; a[rt][7] = (_Float16)x1.w;
            }
        }
#pragma unroll
        for (int c = 0; c < MT; c++) {
            int n = 16 * c + lr;
            int byte = n * 256 + (((k0 + lk * 8) * 2) ^ ((n & 7) << 4));
            f16x8 b = *reinterpret_cast<const f16x8*>(&ldsb[byte]);
            acc[0][c] = __builtin_amdgcn_mfma_f32_16x16x32_f16(a[0], b, acc[0][c], 0, 0, 0);
            acc[1][c] = __builtin_amdgcn_mfma_f32_16x16x32_f16(a[1], b, acc[1][c], 0, 0, 0);
        }
    }
    __syncthreads();

#pragma unroll
    for (int rt = 0; rt < 2; rt++)
#pragma unroll
        for (int c = 0; c < MT; c++)
#pragma unroll
            for (int r = 0; r < 4; r++) {
                int rowl = rt * 64 + wv * 16 + lk * 4 + r;
                int col = 16 * c + lr;
                int byte = rowl * HST + ((col * 2) ^ ((rowl & 7) << 4));
                *reinterpret_cast<__half*>(&ldsb[byte]) = __float2half(acc[rt][c][r]);
            }
    __syncthreads();

    int row = tid >> 1, seg = tid & 1;
    int rowg = blockIdx.x * 128 + row;
    if (rowg < N) {
        const int rowB = Mout * 2;
        int segstart = (MT == 8) ? seg * 128 : seg * 48;
        int nch = (MT == 8) ? 8 : (seg ? 2 : 3);
        float hs[H], hd[H];
#pragma unroll
        for (int h = 0; h < H; h++) { hs[h] = 0.f; hd[h] = 0.f; }
        for (int i = 0; i < nch; i++) {
            int cb = segstart + i * 16;
            f16x8 v = *reinterpret_cast<const f16x8*>(
                &ldsb[row * HST + (cb ^ ((row & 7) << 4))]);
            *reinterpret_cast<f16x8*>((char*)Hout + (size_t)rowg * rowB + cb) = v;
            int hh = (H == 1) ? 0 : (cb >> 6);
            int colb = cb >> 1;
            float ps = 0.f, pd = 0.f;
#pragma unroll
            for (int j = 0; j < 8; j++) {
                float f = (float)v[j];
                ps = fmaf(f, a_src[colb + j], ps);
                pd = fmaf(f, a_dst[colb + j], pd);
            }
            hs[hh] += ps; hd[hh] += pd;
        }
        if (H == 4) {
#pragma unroll
            for (int t = 0; t < 2; t++) {
                int hh = 2 * seg + t;
                als[rowg * 4 + hh] = hs[hh];
                ald[rowg * 4 + hh] = hd[hh];
                atomicMax(&lmax[hh], f2oi(hs[hh]));
                atomicMax(&lmax[4 + hh], f2oi(hd[hh]));
            }
        } else {
            float s = hs[0] + __shfl_xor(hs[0], 1, 64);
            float d = hd[0] + __shfl_xor(hd[0], 1, 64);
            if (seg == 0) {
                als[rowg] = s; ald[rowg] = d;
                atomicMax(&lmax[0], f2oi(s));
                atomicMax(&lmax[4], f2oi(d));
            }
        }
    }
    __syncthreads();
    if (tid < H) atomicMax(&mint[tid], lmax[tid]);
    if (tid >= 8 && tid < 8 + H) atomicMax(&mint[4 + tid - 8], lmax[4 + tid - 8]);
}

// ---------- atomic-free CSR build (packed src<<16|dst pairs; N < 65536) ----------
__global__ __launch_bounds__(256) void p1_hist(const int* __restrict__ src,
                                               const int* __restrict__ dst,
                                               int E_real, int E_tot, int NB, int NBLK,
                                               int EPB, int* __restrict__ cntmat,
                                               int* __restrict__ mint) {
    if (blockIdx.x == 0 && threadIdx.x < 24) mint[threadIdx.x] = (int)0x80000000;
    __shared__ int hist[1024];
    for (int i = threadIdx.x; i < NB; i += 256) hist[i] = 0;
    __syncthreads();
    int e0 = blockIdx.x * EPB;
    int e1 = min(e0 + EPB, E_tot);
    for (int e = e0 + threadIdx.x; e < e1; e += 256) {
        int d = (e < E_real) ? dst[e] : e - E_real;
        atomicAdd(&hist[d >> 6], 1);
    }
    __syncthreads();
    for (int b = threadIdx.x; b < NB; b += 256)
        cntmat[b * NBLK + blockIdx.x] = hist[b];
}

__global__ __launch_bounds__(256) void p_scancols(int* __restrict__ cntmat,
                                                  int* __restrict__ colTot, int NBLK) {
    __shared__ int sh[256];
    int b = blockIdx.x;
    int t = threadIdx.x;
    if (t < NBLK) sh[t] = cntmat[b * NBLK + t];
    __syncthreads();
    if (t == 0) {
        int run = 0;
        for (int i = 0; i < NBLK; i++) { int v = sh[i]; sh[i] = run; run += v; }
        colTot[b] = run;
    }
    __syncthreads();
    if (t < NBLK) cntmat[b * NBLK + t] = sh[t];
}

__global__ __launch_bounds__(256) void p_scancoarse(const int* __restrict__ colTot,
                                                    int* __restrict__ coarseOff,
                                                    int* __restrict__ offsets,
                                                    int NB, int N, int E_tot) {
    __shared__ int sh[256];
    int t = threadIdx.x, base = t * 4;
    int v0 = 0, v1 = 0, v2 = 0, v3 = 0;
    if (base + 0 < NB) v0 = colTot[base + 0];
    if (base + 1 < NB) v1 = colTot[base + 1];
    if (base + 2 < NB) v2 = colTot[base + 2];
    if (base + 3 < NB) v3 = colTot[base + 3];
    int s = v0 + v1 + v2 + v3;
    sh[t] = s;
    __syncthreads();
    for (int off = 1; off < 256; off <<= 1) {
        int u = (t >= off) ? sh[t - off] : 0;
        __syncthreads();
        sh[t] += u;
        __syncthreads();
    }
    int run = sh[t] - s;
    if (base + 0 < NB) { coarseOff[base + 0] = run; run += v0; }
    if (base + 1 < NB) { coarseOff[base + 1] = run; run += v1; }
    if (base + 2 < NB) { coarseOff[base + 2] = run; run += v2; }
    if (base + 3 < NB) { coarseOff[base + 3] = run; }
    if (t == 255) { coarseOff[NB] = sh[255]; offsets[N] = E_tot; }
}

__global__ __launch_bounds__(256) void p2_scatter(const int* __restrict__ src,
                                                  const int* __restrict__ dst,
                                                  int E_real, int E_tot, int NB, int NBLK,
                                                  int EPB, const int* __restrict__ cntmat,
                                                  const int* __restrict__ coarseOff,
                                                  int* __restrict__ pairs) {
    __shared__ int cur[1024];
    for (int b = threadIdx.x; b < NB; b += 256)
        cur[b] = coarseOff[b] + cntmat[b * NBLK + blockIdx.x];
    __syncthreads();
    int e0 = blockIdx.x * EPB;
    int e1 = min(e0 + EPB, E_tot);
    for (int e = e0 + threadIdx.x; e < e1; e += 256) {
        int s, d;
        if (e < E_real) { s = src[e]; d = dst[e]; } else { s = d = e - E_real; }
        int pos = atomicAdd(&cur[d >> 6], 1);
        pairs[pos] = (s << 16) | d;
    }
}

__global__ __launch_bounds__(256) void p3_bucket(const int* __restrict__ pairs,
                                                 const int* __restrict__ coarseOff,
                                                 int NB, int N, int* __restrict__ offsets,
                                                 int* __restrict__ csr_src) {
    __shared__ int lh[64], lc[64];
    int b = blockIdx.x;
    int beg = coarseOff[b], end = coarseOff[b + 1];
    int t = threadIdx.x;
    if (t < 64) lh[t] = 0;
    __syncthreads();
    for (int i = beg + t; i < end; i += 256)
        atomicAdd(&lh[pairs[i] & 63], 1);
    __syncthreads();
    if (t < 64) {
        int v = lh[t];
        int run = v;
#pragma unroll
        for (int off = 1; off < 64; off <<= 1) {
            int o = __shfl_up(run, off, 64);
            if (t >= off) run += o;
        }
        int ex = run - v;
        lc[t] = ex;
        int node = b * 64 + t;
        if (node < N) offsets[node] = beg + ex;
    }
    __syncthreads();
    for (int i = beg + t; i < end; i += 256) {
        int pk = pairs[i];
        int pos = atomicAdd(&lc[pk & 63], 1);
        csr_src[beg + pos] = ((unsigned)pk) >> 16;
    }
}

// ---------- GAT aggregate, layers 0/1 (H=4,C=32): 4 edges in flight, fp16 out ----------
__global__ __launch_bounds__(256) void gat_agg128(const int* __restrict__ offsets,
                                                  const int* __restrict__ csr_src,
                                                  const __half* __restrict__ h,
                                                  const float* __restrict__ als,
                                                  const float* __restrict__ ald,
                                                  const int* __restrict__ mint,
                                                  const float* __restrict__ bias,
                                                  __half* __restrict__ out, int N) {
    __shared__ float wlds[4][64][4];
    __shared__ int   slds[4][64];
    int wid = threadIdx.x >> 6;
    int lane = threadIdx.x & 63;
    int g = lane >> 4, j = lane & 15, hd = j >> 2;
    int gwid = (blockIdx.x * 256 + threadIdx.x) >> 6;
    int nWaves = (gridDim.x * 256) >> 6;
    const char* hb = (const char*)h;
    const float4* als4 = (const float4*)als;
    const float4* ald4 = (const float4*)ald;

    float4 shiftv;
    {
        float v;
        v = oi2f(mint[0]) + oi2f(mint[4]); shiftv.x = v > 0.f ? v : 0.2f * v;
        v = oi2f(mint[1]) + oi2f(mint[5]); shiftv.y = v > 0.f ? v : 0.2f * v;
        v = oi2f(mint[2]) + oi2f(mint[6]); shiftv.z = v > 0.f ? v : 0.2f * v;
        v = oi2f(mint[3]) + oi2f(mint[7]); shiftv.w = v > 0.f ? v : 0.2f * v;
    }
    float4 bv0 = ((const float4*)bias)[j * 2];
    float4 bv1 = ((const float4*)bias)[j * 2 + 1];

    for (int n = gwid; n < N; n += nWaves) {
        int beg = offsets[n], end = offsets[n + 1];
        float4 adn = ald4[n];
        float acc[8];
#pragma unroll
        for (int k = 0; k < 8; k++) acc[k] = 0.f;
        float den = 0.f;

        for (int c0 = beg; c0 < end; c0 += 64) {
            int e = c0 + lane;
            int s = 0;
            float4 w = make_float4(0.f, 0.f, 0.f, 0.f);
            if (e < end) {
                s = csr_src[e];
                float4 a4 = als4[s];
                float v;
                v = a4.x + adn.x; v = v > 0.f ? v : 0.2f * v; w.x = __expf(v - shiftv.x);
                v = a4.y + adn.y; v = v > 0.f ? v : 0.2f * v; w.y = __expf(v - shiftv.y);
                v = a4.z + adn.z; v = v > 0.f ? v : 0.2f * v; w.z = __expf(v - shiftv.z);
                v = a4.w + adn.w; v = v > 0.f ? v : 0.2f * v; w.w = __expf(v - shiftv.w);
            }
            *reinterpret_cast<float4*>(&wlds[wid][lane][0]) = w;
            slds[wid][lane] = s;
            int cnt = end - c0; if (cnt > 64) cnt = 64;
            int quads = (cnt + 3) >> 2;
            for (int q = 0; q < quads; ++q) {
                int ec = q * 4 + g;
                int s0 = slds[wid][ec];
                float w0 = wlds[wid][ec][hd];
                f16x8 hv = *reinterpret_cast<const f16x8*>(
                    hb + (unsigned)(s0 * 256 + j * 16));
                den += w0;
#pragma unroll
                for (int k = 0; k < 8; k++)
                    acc[k] = fmaf((float)hv[k], w0, acc[k]);
            }
        }
#pragma unroll
        for (int off = 16; off <= 32; off <<= 1) {
            den += __shfl_xor(den, off, 64);
#pragma unroll
            for (int k = 0; k < 8; k++) acc[k] += __shfl_xor(acc[k], off, 64);
        }
        if (g == 0) {
            float inv = 1.f / den;
            f16x8 ov;
            float bvv[8] = {bv0.x, bv0.y, bv0.z, bv0.w, bv1.x, bv1.y, bv1.z, bv1.w};
#pragma unroll
            for (int k = 0; k < 8; k++) {
                float r = acc[k] * inv + bvv[k];
                r = r > 0.f ? r : __expf(r) - 1.f;
                ov[k] = (_Float16)r;
            }
            *reinterpret_cast<f16x8*>((char*)out + (size_t)n * 256 + j * 16) = ov;
        }
    }
}

// ---------- GAT aggregate + log_softmax, layer 2 (H=1,C=40) ----------
__global__ __launch_bounds__(256) void gat_agg40_lsm(const int* __restrict__ offsets,
                                                     const int* __restrict__ csr_src,
                                                     const __half* __restrict__ h,
                                                     const float* __restrict__ als,
                                                     const float* __restrict__ ald,
                                                     const int* __restrict__ mint,
                                                     const float* __restrict__ b2,
                                                     float* __restrict__ out, int N) {
    __shared__ float wlds[4][64];
    __shared__ int   slds[4][64];
    int wid = threadIdx.x >> 6;
    int lane = threadIdx.x & 63;
    int g = lane >> 4, j = lane & 15;
    int gwid = (blockIdx.x * 256 + threadIdx.x) >> 6;
    int nWaves = (gridDim.x * 256) >> 6;
    const char* hb = (const char*)h;

    float shift;
    {
        float v = oi2f(mint[0]) + oi2f(mint[4]);
        shift = v > 0.f ? v : 0.2f * v;
    }
    float4 bv = (j < 10) ? ((const float4*)b2)[j] : make_float4(0.f, 0.f, 0.f, 0.f);

    for (int n = gwid; n < N; n += nWaves) {
        int beg = offsets[n], end = offsets[n + 1];
        float adn = ald[n];
        float acc[4];
#pragma unroll
        for (int k = 0; k < 4; k++) acc[k] = 0.f;
        float den = 0.f;

        for (int c0 = beg; c0 < end; c0 += 64) {
            int e = c0 + lane;
            int s = 0;
            float wv = 0.f;
            if (e < end) {
                s = csr_src[e];
                float v = als[s] + adn; v = v > 0.f ? v : 0.2f * v;
                wv = __expf(v - shift);
            }
            wlds[wid][lane] = wv;
            slds[wid][lane] = s;
            int cnt = end - c0; if (cnt > 64) cnt = 64;
            int quads = (cnt + 3) >> 2;
            for (int q = 0; q < quads; ++q) {
                int ec = q * 4 + g;
                int s0 = slds[wid][ec];
                float w0 = wlds[wid][ec];
                den += w0;
                if (j < 10) {
                    f16x4 hv = *reinterpret_cast<const f16x4*>(
                        hb + (unsigned)(s0 * 80 + j * 8));
#pragma unroll
                    for (int k = 0; k < 4; k++)
                        acc[k] = fmaf((float)hv[k], w0, acc[k]);
                }
            }
        }
#pragma unroll
        for (int off = 16; off <= 32; off <<= 1) {
            den += __shfl_xor(den, off, 64);
#pragma unroll
            for (int k = 0; k < 4; k++) acc[k] += __shfl_xor(acc[k], off, 64);
        }
        float inv = 1.f / den;
        float val[4];
        float m = -INFINITY;
#pragma unroll
        for (int k = 0; k < 4; k++) {
            val[k] = (j < 10) ? acc[k] * inv + ((const float*)&bv)[k] : -INFINITY;
            m = fmaxf(m, val[k]);
        }
#pragma unroll
        for (int off = 8; off >= 1; off >>= 1) m = fmaxf(m, __shfl_xor(m, off, 64));
        float pe = 0.f;
#pragma unroll
        for (int k = 0; k < 4; k++)
            if (j < 10) pe += __expf(val[k] - m);
#pragma unroll
        for (int off = 8; off >= 1; off >>= 1) pe += __shfl_xor(pe, off, 64);
        if (g == 0 && j < 10) {
            float lsum = __logf(pe);
            float4 o;
            o.x = val[0] - m - lsum;
            o.y = val[1] - m - lsum;
            o.z = val[2] - m - lsum;
            o.w = val[3] - m - lsum;
            ((float4*)(out + (size_t)n * 40))[j] = o;
        }
    }
}

extern "C" void kernel_launch(void* const* d_in, const int* in_sizes, int n_in,
                              void* d_out, int out_size, void* d_ws, size_t ws_size,
                              hipStream_t stream) {
    const float* x      = (const float*)d_in[0];
    const int*   ei     = (const int*)d_in[1];
    const float* W0     = (const float*)d_in[2];
    const float* a_src0 = (const float*)d_in[3];
    const float* a_dst0 = (const float*)d_in[4];
    const float* b0     = (const float*)d_in[5];
    const float* W1     = (const float*)d_in[6];
    const float* a_src1 = (const float*)d_in[7];
    const float* a_dst1 = (const float*)d_in[8];
    const float* b1     = (const float*)d_in[9];
    const float* W2     = (const float*)d_in[10];
    const float* a_src2 = (const float*)d_in[11];
    const float* a_dst2 = (const float*)d_in[12];
    const float* b2     = (const float*)d_in[13];

    const int N = in_sizes[0] / 128;          // 50000  (< 65536, required for packing)
    const int E_real = in_sizes[1] / 2;       // 800000
    const int E_tot = E_real + N;
    const int* src = ei;
    const int* dst = ei + E_real;

    const int EPB  = 4096;
    const int NBLK = (E_tot + EPB - 1) / EPB; // 208
    const int NB   = (N + 63) >> 6;           // 782

    unsigned char* ws = (unsigned char*)d_ws;
    size_t off = 0;
    __half* bufH    = (__half*)(ws + off); off += (size_t)N * 128 * sizeof(__half);
    __half* bufAcc  = (__half*)(ws + off); off += (size_t)N * 128 * sizeof(__half);
    int*    csr_src = (int*)(ws + off);    off += (size_t)E_tot * sizeof(int);
    int*    pairs   = (int*)(ws + off);    off += (size_t)E_tot * sizeof(int);
    float*  als     = (float*)(ws + off);  off += (size_t)N * 4 * sizeof(float);
    float*  ald     = (float*)(ws + off);  off += (size_t)N * 4 * sizeof(float);
    int*    offsets = (int*)(ws + off);    off += (size_t)(N + 1) * sizeof(int);
    int*    colTot  = (int*)(ws + off);    off += (size_t)NB * sizeof(int);
    int*    coarseOff = (int*)(ws + off);  off += (size_t)(NB + 1) * sizeof(int);
    int*    mint    = (int*)(ws + off);    off += 24 * sizeof(int);
    int*    cntmat  = (int*)(ws + off);    off += (size_t)NB * NBLK * sizeof(int);

    const int B = 256;
    const int gRows128 = (N + 127) / 128;
    const int gAgg  = 2048;

    // ===== CSR build (atomic-free; mint init fused into p1) =====
    p1_hist<<<NBLK, B, 0, stream>>>(src, dst, E_real, E_tot, NB, NBLK, EPB, cntmat, mint);
    p_scancols<<<NB, B, 0, stream>>>(cntmat, colTot, NBLK);
    p_scancoarse<<<1, B, 0, stream>>>(colTot, coarseOff, offsets, NB, N, E_tot);
    p2_scatter<<<NBLK, B, 0, stream>>>(src, dst, E_real, E_tot, NB, NBLK, EPB, cntmat, coarseOff, pairs);
    p3_bucket<<<NB, B, 0, stream>>>(pairs, coarseOff, NB, N, offsets, csr_src);

    // ===== Layer 0 =====
    gemm_mfma<8, 4, false><<<gRows128, B, 0, stream>>>(x, W0, a_src0, a_dst0, bufH, 128, als, ald, mint, N);
    gat_agg128<<<gAgg, B, 0, stream>>>(offsets, csr_src, bufH, als, ald, mint, b0, bufAcc, N);

    // ===== Layer 1 =====
    gemm_mfma<8, 4, true><<<gRows128, B, 0, stream>>>(bufAcc, W1, a_src1, a_dst1, bufH, 128, als, ald, mint + 8, N);
    gat_agg128<<<gAgg, B, 0, stream>>>(offsets, csr_src, bufH, als, ald, mint + 8, b1, bufAcc, N);

    // ===== Layer 2 =====
    gemm_mfma<3, 1, true><<<gRows128, B, 0, stream>>>(bufAcc, W2, a_src2, a_dst2, bufH, 40, als, ald, mint + 16, N);
    gat_agg40_lsm<<<gAgg, B, 0, stream>>>(offsets, csr_src, bufH, als, ald, mint + 16, b2,
                                          (float*)d_out, N);
}